// Round 5
// baseline (1341.066 us; speedup 1.0000x reference)
//
#include <hip/hip_runtime.h>
#include <hip/hip_bf16.h>

// DTGCN: B=16,N=256,T=64,W=12,H=64,ED=64,S=5,C=4,E=2048, FG=76
// R20 (de-staging pass on R19 structure):
//  - Direct global->register MFMA fragments. The staged LDS tiles (ItT for h,
//    j1/j2 for de) held byte-identical u64 pairs from the published buffers:
//      h b-frag(feat,ch,quad) = hgpb[feat*64 + ch*8 + quad*2 .. +1]
//      de a-frag(row,ks,quad) = de1g[row*16 + ks*8 + quad*2 .. +1]
//    Loading frags directly removes barriers A1,A2,P3-1,P3-2,P3-3 (13->7
//    barriers/step), all staging ds_write/ds_read + index VALU, and the
//    th/tw/t1/t2 register round-trips. MALL volume unchanged (verified).
//  - Per-wave release tags for de and h publishes: each wave drains its own
//    stores (inline s_waitcnt vmcnt(0)) and lane0 publishes tags[wg*4+wv].
//    Consumers poll 32 wave-tags per half (same 2-serial-poll structure).
//    Barrier P4-4 removed entirely.
//  - s_colv reset moved to phase-A tail (pre-A5) for cross-wave safety now
//    that P3 has no internal barriers.
//  - Eh store/load, deg epoch-units, de reg-publish, classifier: as R19.

typedef unsigned short u16;
typedef unsigned int u32;
typedef unsigned long long u64;
typedef __attribute__((ext_vector_type(8))) short bf16x8;
typedef __attribute__((ext_vector_type(4))) float f32x4;

#define B_ 16
#define N_ 256
#define T_ 64
#define W_ 12
#define S_ 5
#define E_ 2048
#define G_ 16

__device__ __forceinline__ float b2f(u16 u) {
  union { u32 i; float f; } v; v.i = ((u32)u) << 16; return v.f;
}
__device__ __forceinline__ u16 f2b(float f) {
  union { float f; u32 i; } v; v.f = f;
  u32 x = v.i; x += 0x7fff + ((x >> 16) & 1); return (u16)(x >> 16);
}
__device__ __forceinline__ float ftanh(float x) {
  float e = __expf(-2.f * fabsf(x));
  float t = (1.f - e) / (1.f + e);
  return x < 0.f ? -t : t;
}
__device__ __forceinline__ float fsigm(float x) { return 1.f / (1.f + __expf(-x)); }
__device__ __forceinline__ float cvload(const void* p, size_t i, int f) {
  return f ? ((const float*)p)[i] : b2f(((const u16*)p)[i]);
}
__device__ __forceinline__ u16 cvloadb(const void* p, size_t i, int f) {
  return f ? f2b(((const float*)p)[i]) : ((const u16*)p)[i];
}
__device__ __forceinline__ float gld(const float* p) {
  return __hip_atomic_load(p, __ATOMIC_RELAXED, __HIP_MEMORY_SCOPE_SYSTEM);
}
__device__ __forceinline__ void gst(float* p, float v) {
  __hip_atomic_store(p, v, __ATOMIC_RELAXED, __HIP_MEMORY_SCOPE_SYSTEM);
}
__device__ __forceinline__ u64 gld64(const u64* p) {
  return __hip_atomic_load(p, __ATOMIC_RELAXED, __HIP_MEMORY_SCOPE_SYSTEM);
}
__device__ __forceinline__ void gst64(u64* p, u64 v) {
  __hip_atomic_store(p, v, __ATOMIC_RELAXED, __HIP_MEMORY_SCOPE_SYSTEM);
}
__device__ __forceinline__ u32 gldu(const u32* p) {
  return __hip_atomic_load(p, __ATOMIC_RELAXED, __HIP_MEMORY_SCOPE_SYSTEM);
}
__device__ __forceinline__ f32x4 mfma16(bf16x8 a, bf16x8 b, f32x4 c) {
  return __builtin_amdgcn_mfma_f32_16x16x32_bf16(a, b, c, 0, 0, 0);
}
__device__ __forceinline__ bf16x8 ldfrag(const u16* p) { return *(const bf16x8*)p; }
__device__ __forceinline__ bf16x8 mkfrag(u64 lo, u64 hi) {
  union { u64 q[2]; bf16x8 v; } u; u.q[0] = lo; u.q[1] = hi; return u.v;
}

struct Params {
  const void *x0, *ew0, *gw0, *gb0, *w10, *b10, *w20, *b20;
  const void *wzc0, *bzc0, *wzl0, *bzl0, *wrc0, *brc0, *wrl0, *brl0;
  const void *whc0, *bhc0, *whl0, *bhl0, *clsw0, *clsb0;
  const int* eidx;
  float *Eh, *clspart;
  u64 *degsum, *de1g, *de2g, *xTp, *hgpT;
  u32 *tags;
  void* out;
};

__device__ __forceinline__ void wtag(const u32* tg, u32 target) {
  const int k = threadIdx.x & 15;
  while (!__all((int)(gldu(&tg[k]) >= target)))
    __builtin_amdgcn_s_sleep(1);
}
__device__ __forceinline__ void wtag32(const u32* tg, int base, u32 target) {
  const int k = base + (threadIdx.x & 31);
  while (!__all((int)(gldu(&tg[k]) >= target)))
    __builtin_amdgcn_s_sleep(1);
}
__device__ __forceinline__ void ptag(u32* tg, int wg, u32 val) {
  if (threadIdx.x == 0)
    __hip_atomic_store(&tg[wg], val, __ATOMIC_RELAXED, __HIP_MEMORY_SCOPE_SYSTEM);
}
// per-wave tag: drain own wave's stores, then lane0 publishes (data-before-tag)
__device__ __forceinline__ void ptagw(u32* tg, int slot, u32 val) {
  asm volatile("s_waitcnt vmcnt(0)" ::: "memory");
  if ((threadIdx.x & 63) == 0)
    __hip_atomic_store(&tg[slot], val, __ATOMIC_RELAXED, __HIP_MEMORY_SCOPE_SYSTEM);
}

// ================= main persistent kernel (prologue + loop + cls tail) ======
__global__ void __launch_bounds__(256, 1) dtgcn_main(Params p) {
  __shared__ __align__(16) u16 s_union[8704];    // prologue scratch only
  __shared__ __align__(16) u16 s_gwF[64 * 104];
  __shared__ __align__(16) u16 s_w1T[64 * 72], s_w2T[64 * 72];
  __shared__ __align__(16) u16 s_gzT[64 * 72], s_grT[64 * 72], s_ghT[64 * 72];
  __shared__ __align__(16) u16 s_antO1[16 * 264], s_antO2[16 * 264];
  __shared__ __align__(16) u16 s_m1[16 * 104];
  __shared__ float s_msum[16 * 257];
  __shared__ __align__(16) u16 s_de1I[16 * 72], s_de2I[16 * 72];
  __shared__ __align__(16) u16 s_hbf[16 * 72];
  __shared__ __align__(16) u16 s_dfhr[16 * 72];
  __shared__ float s_colv[16], s_degacc[16];
  __shared__ float s_y[256], s_dinv[256], s_s[16];
  __shared__ float s_uv[384], s_gb[64], s_b1[64], s_b2[64];
  __shared__ int s_flag;

  const int b = blockIdx.x & 15;
  const int wg = blockIdx.x >> 4;
  const int tid = threadIdx.x;
  const int lane = tid & 63;
  const int wv = tid >> 6;
  const int l = lane & 15;
  const int quad = lane >> 4;
  const int r0 = wg * 16;

  u64* de1g = p.de1g + (size_t)b * N_ * 16;
  u64* de2g = p.de2g + (size_t)b * N_ * 16;
  u64* hgpb = p.hgpT + (size_t)b * 64 * 64;
  u64* xTw  = p.xTp + (size_t)b * 64 * 64;
  const u64* xTb = xTw;
  u64* degb = p.degsum + (size_t)b * N_;           // epoch units
  u32* tgDe4 = p.tags + b * 256;                   // 64 wave-tags
  u32* tgH4  = p.tags + b * 256 + 64;              // 64 wave-tags
  u32* tgX   = p.tags + b * 256 + 128;             // 16
  u32* tgC   = p.tags + b * 256 + 144;             // 16

  // ================= prologue =================
  // 1) dtype detect
  if (tid == 0) {
    const u16* q = (const u16*)p.x0;
    int c = 0;
    for (int i = 0; i < 256; ++i) {
      int ex = (q[i] >> 7) & 0xff;
      c += (ex >= 110 && ex <= 135);
    }
    s_flag = (c < 200) ? 1 : 0;   // 1 = fp32 inputs
  }
  __syncthreads();
  const int fl = s_flag;

  // 2) x^T build: this WG handles t rows [4wg, 4wg+4)
  {
    u16* xs = s_union;   // [4][256]
    #pragma unroll
    for (int r = 0; r < 4; ++r) {
      const int tt = wg * 4 + r;
      xs[r * 256 + tid] = f2b(cvload(p.x0, ((size_t)b * N_ + tid) * T_ + tt, fl));
    }
    __syncthreads();
    const int r = tid >> 6, c = tid & 63;
    u64 v = (u64)xs[r * 256 + 4 * c]
          | ((u64)xs[r * 256 + 4 * c + 1] << 16)
          | ((u64)xs[r * 256 + 4 * c + 2] << 32)
          | ((u64)xs[r * 256 + 4 * c + 3] << 48);
    gst64(&xTw[(size_t)(wg * 4 + r) * 64 + c], v);
    __syncthreads();
    ptag(tgX, wg, 1);
  }

  // 3) WG-local A-normalization (split-bf16 A^T own columns)
  {
    float* s_acol = (float*)s_union;          // [256][16]
    float* s_dg   = (float*)s_union + 4096;   // [256]
    for (int i = tid; i < 4096; i += 256) s_acol[i] = 0.f;
    s_dg[tid] = 0.f;
    __syncthreads();
    for (int e2 = tid; e2 < E_; e2 += 256) {
      const int sN = p.eidx[e2], dN = p.eidx[E_ + e2];
      const float wv2 = cvload(p.ew0, e2, fl);
      atomicAdd(&s_dg[dN], wv2);
      const int dl = dN - r0;
      if (dl >= 0 && dl < 16) atomicAdd(&s_acol[sN * 16 + dl], wv2);
    }
    __syncthreads();
    s_dg[tid] = rsqrtf(1.f + s_dg[tid]);
    __syncthreads();
    for (int idx = tid; idx < 4096; idx += 256) {
      const int jl = idx >> 8, i = idx & 255;
      float a = s_acol[i * 16 + jl] + ((i == r0 + jl) ? 1.f : 0.f);
      float v = s_dg[i] * a * s_dg[r0 + jl];
      u16 hi = f2b(v);
      s_antO1[jl * 264 + i] = hi;
      s_antO2[jl * 264 + i] = f2b(v - b2f(hi));
    }
  }

  // 4) weights / uv / biases / zeroing
  for (int idx = tid; idx < 64 * 104; idx += 256) {
    const int ee = idx / 104, k = idx - ee * 104;
    u16 v = 0;
    if (k < 64) v = cvloadb(p.gw0, (12 + k) * 64 + ee, fl);
    else if (k < 76) v = cvloadb(p.gw0, (k - 64) * 64 + ee, fl);
    s_gwF[ee * 104 + k] = v;
  }
  for (int idx = tid; idx < 4096; idx += 256) {
    const int ee = idx >> 6, ff = idx & 63;
    s_w1T[ee * 72 + ff] = cvloadb(p.w10, ff * 64 + ee, fl);
    s_w2T[ee * 72 + ff] = cvloadb(p.w20, ff * 64 + ee, fl);
    s_gzT[ee * 72 + ff] = cvloadb(p.wzl0, 4096 + ff * 64 + ee, fl);
    s_grT[ee * 72 + ff] = cvloadb(p.wrl0, 4096 + ff * 64 + ee, fl);
    s_ghT[ee * 72 + ff] = cvloadb(p.whl0, 4096 + ff * 64 + ee, fl);
  }
  if (tid < 64) {
    const int e2 = tid;
    float uz = 0, vz = 0, ur = 0, vr = 0, uh = 0, vh = 0;
    for (int f = 0; f < 64; ++f) {
      float wz = cvload(p.wzl0, f * 64 + e2, fl);
      float wr = cvload(p.wrl0, f * 64 + e2, fl);
      float wh = cvload(p.whl0, f * 64 + e2, fl);
      uz += cvload(p.wzc0, f, fl) * wz; vz += cvload(p.bzc0, f, fl) * wz;
      ur += cvload(p.wrc0, f, fl) * wr; vr += cvload(p.brc0, f, fl) * wr;
      uh += cvload(p.whc0, f, fl) * wh; vh += cvload(p.bhc0, f, fl) * wh;
    }
    s_uv[0 * 64 + e2] = uz; s_uv[1 * 64 + e2] = vz + cvload(p.bzl0, e2, fl);
    s_uv[2 * 64 + e2] = ur; s_uv[3 * 64 + e2] = vr + cvload(p.brl0, e2, fl);
    s_uv[4 * 64 + e2] = uh; s_uv[5 * 64 + e2] = vh + cvload(p.bhl0, e2, fl);
    s_gb[tid] = cvload(p.gb0, tid, fl);
    s_b1[tid] = cvload(p.b10, tid, fl);
    s_b2[tid] = cvload(p.b20, tid, fl);
  }
  for (int idx = tid; idx < 16 * 257; idx += 256) s_msum[idx] = 0.f;
  for (int idx = tid; idx < 16 * 72; idx += 256) s_hbf[idx] = 0;
  for (int idx = tid; idx < 16 * 104; idx += 256) s_m1[idx] = 0;  // cols>=80 stay 0
  if (tid < 16) s_degacc[tid] = 0.f;
  __syncthreads();

  float hreg[4] = {0.f, 0.f, 0.f, 0.f};
  const int e = wv * 16 + l;

  for (int t = 0; t < T_; ++t) {
    float xv;
    // ---------- phase A: M1 (direct frags), df, de ----------
    {
      if (t == 0) wtag(tgX, 1);
      // prefetch x[t] for P4 (no dependencies)
      xv = cvload(p.x0, ((size_t)b * N_ + tid) * T_ + t, fl);
      // window tile (channels 64..79) — wave 0 only, xT static, no tag
      u64 b2l[8][2];
      if (wv == 0) {
        const int tx = t - (W_ - 1) + l;
        const bool live = (l < W_) && (tx >= 0);
        #pragma unroll
        for (int ch = 0; ch < 8; ++ch) {
          b2l[ch][0] = live ? gld64(&xTb[(size_t)tx * 64 + ch * 8 + quad * 2]) : 0ull;
          b2l[ch][1] = live ? gld64(&xTb[(size_t)tx * 64 + ch * 8 + quad * 2 + 1]) : 0ull;
        }
      }
      const u32 htgt = (u32)t;
      u64 b1l[8][2];
      // half 0 producers (WGs 0..7 => nodes 0..127 => chunks 0..3)
      wtag32(tgH4, 0, htgt);
      #pragma unroll
      for (int ch = 0; ch < 4; ++ch) {
        b1l[ch][0] = gld64(&hgpb[(size_t)e * 64 + ch * 8 + quad * 2]);
        b1l[ch][1] = gld64(&hgpb[(size_t)e * 64 + ch * 8 + quad * 2 + 1]);
      }
      // half 1 producers (chunks 4..7)
      wtag32(tgH4, 32, htgt);
      #pragma unroll
      for (int ch = 4; ch < 8; ++ch) {
        b1l[ch][0] = gld64(&hgpb[(size_t)e * 64 + ch * 8 + quad * 2]);
        b1l[ch][1] = gld64(&hgpb[(size_t)e * 64 + ch * 8 + quad * 2 + 1]);
      }
      // M1 tile 1: channel column e (all waves)
      f32x4 acc0 = {0.f, 0.f, 0.f, 0.f};
      #pragma unroll
      for (int ch = 0; ch < 8; ++ch) {
        bf16x8 bfr = mkfrag(b1l[ch][0], b1l[ch][1]);
        const int io = ch * 32 + quad * 8;
        acc0 = mfma16(ldfrag(&s_antO1[l * 264 + io]), bfr, acc0);
        acc0 = mfma16(ldfrag(&s_antO2[l * 264 + io]), bfr, acc0);
      }
      #pragma unroll
      for (int r = 0; r < 4; ++r)
        s_m1[(quad * 4 + r) * 104 + e] = f2b(acc0[r]);
      // M1 tile 2: window channels 64..79 (wave 0)
      if (wv == 0) {
        f32x4 acc1 = {0.f, 0.f, 0.f, 0.f};
        #pragma unroll
        for (int ch = 0; ch < 8; ++ch) {
          bf16x8 bfr = mkfrag(b2l[ch][0], b2l[ch][1]);
          const int io = ch * 32 + quad * 8;
          acc1 = mfma16(ldfrag(&s_antO1[l * 264 + io]), bfr, acc1);
          acc1 = mfma16(ldfrag(&s_antO2[l * 264 + io]), bfr, acc1);
        }
        #pragma unroll
        for (int r = 0; r < 4; ++r)
          s_m1[(quad * 4 + r) * 104 + 64 + l] = f2b(acc1[r]);
      }
      __syncthreads();                       // bar A3: m1 ready
      // df = M1 @ gw + gb (K=96, cols>=80 zero)
      {
        f32x4 dfa = {0.f, 0.f, 0.f, 0.f};
        #pragma unroll
        for (int ks = 0; ks < 3; ++ks) {
          bf16x8 afr = ldfrag(&s_m1[l * 104 + ks * 32 + quad * 8]);
          dfa = mfma16(afr, ldfrag(&s_gwF[e * 104 + ks * 32 + quad * 8]), dfa);
        }
        #pragma unroll
        for (int r = 0; r < 4; ++r)
          s_dfhr[(quad * 4 + r) * 72 + e] = f2b(dfa[r] + s_gb[e]);
      }
      __syncthreads();                       // bar A4
      // de1/de2: compute, publish from regs (shfl-packed), local LDS strips
      {
        f32x4 E1, E2;
        #pragma unroll
        for (int r = 0; r < 4; ++r) { E1[r] = s_b1[e]; E2[r] = s_b2[e]; }
        #pragma unroll
        for (int ks = 0; ks < 2; ++ks) {
          bf16x8 afr = ldfrag(&s_dfhr[l * 72 + ks * 32 + quad * 8]);
          E1 = mfma16(afr, ldfrag(&s_w1T[e * 72 + ks * 32 + quad * 8]), E1);
          E2 = mfma16(afr, ldfrag(&s_w2T[e * 72 + ks * 32 + quad * 8]), E2);
        }
        u32 v1[4], v2[4];
        #pragma unroll
        for (int r = 0; r < 4; ++r) {
          v1[r] = (u32)f2b(ftanh(E1[r]));
          v2[r] = (u32)f2b(ftanh(E2[r]));
          s_de1I[(quad * 4 + r) * 72 + e] = (u16)v1[r];
          s_de2I[(quad * 4 + r) * 72 + e] = (u16)v2[r];
        }
        // pack 4 consecutive feature cols into one u64 per row (lanes l%4==0)
        #pragma unroll
        for (int r = 0; r < 4; ++r) {
          u32 a1 = (u32)__shfl_xor((int)v1[r], 1);
          u32 a2 = (u32)__shfl_xor((int)v2[r], 1);
          u32 ev1 = (l & 1) ? a1 : v1[r], od1 = (l & 1) ? v1[r] : a1;
          u32 ev2 = (l & 1) ? a2 : v2[r], od2 = (l & 1) ? v2[r] : a2;
          u32 w1 = ev1 | (od1 << 16), w2 = ev2 | (od2 << 16);
          u32 x1 = (u32)__shfl_xor((int)w1, 2);
          u32 x2 = (u32)__shfl_xor((int)w2, 2);
          u64 q1 = (l & 2) ? ((u64)x1 | ((u64)w1 << 32)) : ((u64)w1 | ((u64)x1 << 32));
          u64 q2 = (l & 2) ? ((u64)x2 | ((u64)w2 << 32)) : ((u64)w2 | ((u64)x2 << 32));
          if ((l & 3) == 0) {
            const size_t ro = (size_t)(r0 + quad * 4 + r) * 16 + wv * 4 + (l >> 2);
            gst64(&de1g[ro], q1);
            gst64(&de2g[ro], q2);
          }
        }
      }
      ptagw(tgDe4, wg * 4 + wv, (u32)(t + 1));   // per-wave drain + tag
      if (tid < 16) s_colv[tid] = 0.f;           // reset for P3 (barrier-ordered)
      __syncthreads();                       // bar A5: de1I/de2I ready for P3
    }

    // ---------- P3: Et column strip (direct frags); Eh/Msum/deg ----------
    {
      const int sidx = t % S_;
      float* Ehc = p.Eh + ((size_t)((b * S_ + sidx) * G_ + wg)) * (N_ * 16);
      bf16x8 bq1[2], bq2[2];
      #pragma unroll
      for (int ks = 0; ks < 2; ++ks) {
        bq1[ks] = ldfrag(&s_de1I[l * 72 + ks * 32 + quad * 8]);
        bq2[ks] = ldfrag(&s_de2I[l * 72 + ks * 32 + quad * 8]);
      }
      // hoist Eh "old" reads — WG-private plain cached loads, no tag dep
      const int havold = (t >= S_);
      float old0[2][4] = {{0.f, 0.f, 0.f, 0.f}, {0.f, 0.f, 0.f, 0.f}};
      float old1[2][4] = {{0.f, 0.f, 0.f, 0.f}, {0.f, 0.f, 0.f, 0.f}};
      if (havold) {
        #pragma unroll
        for (int mt2 = 0; mt2 < 2; ++mt2) {
          const int mt = wv * 2 + mt2;
          #pragma unroll
          for (int r = 0; r < 4; ++r) {
            const int i0 = mt * 16 + quad * 4 + r;
            old0[mt2][r] = Ehc[(size_t)i0 * 16 + l];
            old1[mt2][r] = Ehc[(size_t)(128 + i0) * 16 + l];
          }
        }
      }
      const u32 dtgt = (u32)(t + 1);
      // half-0 frag loads (rows (wv*2+mt2)*16+l), tag-gated per wave-tags
      wtag32(tgDe4, 0, dtgt);
      u64 a1[2][2][2], a2[2][2][2];
      #pragma unroll
      for (int mt2 = 0; mt2 < 2; ++mt2) {
        const size_t row = (size_t)((wv * 2 + mt2) * 16 + l);
        #pragma unroll
        for (int ks = 0; ks < 2; ++ks) {
          a1[mt2][ks][0] = gld64(&de1g[row * 16 + ks * 8 + quad * 2]);
          a1[mt2][ks][1] = gld64(&de1g[row * 16 + ks * 8 + quad * 2 + 1]);
          a2[mt2][ks][0] = gld64(&de2g[row * 16 + ks * 8 + quad * 2]);
          a2[mt2][ks][1] = gld64(&de2g[row * 16 + ks * 8 + quad * 2 + 1]);
        }
      }
      // half-1 frag loads issued BEFORE half-0 compute (latency hidden)
      wtag32(tgDe4, 32, dtgt);
      u64 c1[2][2][2], c2[2][2][2];
      #pragma unroll
      for (int mt2 = 0; mt2 < 2; ++mt2) {
        const size_t row = (size_t)(128 + (wv * 2 + mt2) * 16 + l);
        #pragma unroll
        for (int ks = 0; ks < 2; ++ks) {
          c1[mt2][ks][0] = gld64(&de1g[row * 16 + ks * 8 + quad * 2]);
          c1[mt2][ks][1] = gld64(&de1g[row * 16 + ks * 8 + quad * 2 + 1]);
          c2[mt2][ks][0] = gld64(&de2g[row * 16 + ks * 8 + quad * 2]);
          c2[mt2][ks][1] = gld64(&de2g[row * 16 + ks * 8 + quad * 2 + 1]);
        }
      }
      float dcacc = 0.f;
      // compute half 0
      #pragma unroll
      for (int mt2 = 0; mt2 < 2; ++mt2) {
        const int mt = wv * 2 + mt2;
        f32x4 D1 = {0.f, 0.f, 0.f, 0.f}, D2 = {0.f, 0.f, 0.f, 0.f};
        #pragma unroll
        for (int ks = 0; ks < 2; ++ks) {
          D1 = mfma16(mkfrag(a1[mt2][ks][0], a1[mt2][ks][1]), bq2[ks], D1);
          D2 = mfma16(mkfrag(a2[mt2][ks][0], a2[mt2][ks][1]), bq1[ks], D2);
        }
        #pragma unroll
        for (int r = 0; r < 4; ++r) {
          const int i = mt * 16 + quad * 4 + r;
          float d = ftanh(D1[r] - D2[r]);
          float eN = fmaxf(d, 0.f);
          float dd = eN - old0[mt2][r];
          Ehc[(size_t)i * 16 + l] = eN;
          s_msum[l * 257 + i] += dd;
          dcacc += dd;
        }
      }
      // compute half 1
      #pragma unroll
      for (int mt2 = 0; mt2 < 2; ++mt2) {
        const int mt = wv * 2 + mt2;
        f32x4 D1 = {0.f, 0.f, 0.f, 0.f}, D2 = {0.f, 0.f, 0.f, 0.f};
        #pragma unroll
        for (int ks = 0; ks < 2; ++ks) {
          D1 = mfma16(mkfrag(c1[mt2][ks][0], c1[mt2][ks][1]), bq2[ks], D1);
          D2 = mfma16(mkfrag(c2[mt2][ks][0], c2[mt2][ks][1]), bq1[ks], D2);
        }
        #pragma unroll
        for (int r = 0; r < 4; ++r) {
          const int i = 128 + mt * 16 + quad * 4 + r;
          float d = ftanh(D1[r] - D2[r]);
          float eN = fmaxf(d, 0.f);
          float dd = eN - old1[mt2][r];
          Ehc[(size_t)i * 16 + l] = eN;
          s_msum[l * 257 + i] += dd;
          dcacc += dd;
        }
      }
      dcacc += __shfl_xor(dcacc, 16);
      dcacc += __shfl_xor(dcacc, 32);
      if (lane < 16) atomicAdd(&s_colv[lane], dcacc);
      __syncthreads();                       // bar P3-4
      if (tid < 16) {
        float nd = s_degacc[tid] + s_colv[tid];
        s_degacc[tid] = nd;
        union { float f; u32 i; } cv; cv.f = nd;
        gst64(&degb[r0 + tid], (u64)cv.i | ((u64)dtgt << 32));
      }
      // no drain barrier / tag: deg units are self-validating
    }

    // ---------- P4: gates, dinv/y, s, GRU, h publish ----------
    {
      f32x4 azh = {0.f, 0.f, 0.f, 0.f}, arh = {0.f, 0.f, 0.f, 0.f};
      #pragma unroll
      for (int ks = 0; ks < 2; ++ks) {
        bf16x8 afr = ldfrag(&s_hbf[l * 72 + ks * 32 + quad * 8]);
        azh = mfma16(afr, ldfrag(&s_gzT[e * 72 + ks * 32 + quad * 8]), azh);
        arh = mfma16(afr, ldfrag(&s_grT[e * 72 + ks * 32 + quad * 8]), arh);
      }
      const u32 dgt = (u32)(t + 1);
      u64 du;
      for (;;) {
        du = gld64(&degb[tid]);
        if (__all((int)((u32)(du >> 32) >= dgt))) break;
        __builtin_amdgcn_s_sleep(1);
      }
      const float cnt = (float)((t + 1 < S_) ? (t + 1) : S_);
      const float invc = 1.f / cnt;
      {
        union { u32 i; float f; } dv; dv.i = (u32)du;
        float dg = 1.f + dv.f * invc;
        float di = rsqrtf(dg);
        s_dinv[tid] = di;
        s_y[tid] = di * xv;                  // xv prefetched in phase A
      }
      __syncthreads();                       // bar P4-1
      // s: remapped owners + k-rotated reads + butterfly reduce
      {
        const int jl = tid >> 4, cc = tid & 15;
        float part = 0.f;
        #pragma unroll
        for (int k = 0; k < 16; ++k) {
          const int i = cc * 16 + ((k + cc) & 15);
          part += s_msum[jl * 257 + i] * s_y[i];
        }
        part += __shfl_xor(part, 1);
        part += __shfl_xor(part, 2);
        part += __shfl_xor(part, 4);
        part += __shfl_xor(part, 8);
        if (cc == 0) {
          const int j = r0 + jl;
          s_s[jl] = s_dinv[j] * (part * invc + s_y[j]);
        }
      }
      __syncthreads();                       // bar P4-2
      float sv[4];
      #pragma unroll
      for (int r = 0; r < 4; ++r) sv[r] = s_s[quad * 4 + r];
      float zz[4], rr2[4];
      #pragma unroll
      for (int r = 0; r < 4; ++r) {
        zz[r]  = fsigm(azh[r] + s_uv[0 * 64 + e] * sv[r] + s_uv[1 * 64 + e]);
        rr2[r] = fsigm(arh[r] + s_uv[2 * 64 + e] * sv[r] + s_uv[3 * 64 + e]);
      }
      #pragma unroll
      for (int r = 0; r < 4; ++r)
        s_dfhr[(quad * 4 + r) * 72 + e] = f2b(hreg[r] * rr2[r]);
      __syncthreads();                       // bar P4-3
      f32x4 ah;
      #pragma unroll
      for (int r = 0; r < 4; ++r) ah[r] = s_uv[4 * 64 + e] * sv[r] + s_uv[5 * 64 + e];
      #pragma unroll
      for (int ks = 0; ks < 2; ++ks) {
        bf16x8 afr = ldfrag(&s_dfhr[l * 72 + ks * 32 + quad * 8]);
        ah = mfma16(afr, ldfrag(&s_ghT[e * 72 + ks * 32 + quad * 8]), ah);
      }
      #pragma unroll
      for (int r = 0; r < 4; ++r) {
        float ht = ftanh(ah[r]);
        hreg[r] = zz[r] * hreg[r] + (1.f - zz[r]) * ht;
      }
      // direct h publish + per-wave tag; no barrier (s_hbf read is far away)
      {
        u16 h0 = f2b(hreg[0]), h1 = f2b(hreg[1]);
        u16 h2 = f2b(hreg[2]), h3 = f2b(hreg[3]);
        u64 hv = (u64)h0 | ((u64)h1 << 16) | ((u64)h2 << 32) | ((u64)h3 << 48);
        gst64(&hgpb[(size_t)e * 64 + (r0 >> 2) + quad], hv);
        s_hbf[(quad * 4 + 0) * 72 + e] = h0;
        s_hbf[(quad * 4 + 1) * 72 + e] = h1;
        s_hbf[(quad * 4 + 2) * 72 + e] = h2;
        s_hbf[(quad * 4 + 3) * 72 + e] = h3;
      }
      ptagw(tgH4, wg * 4 + wv, (u32)(t + 1));
    }
  }

  // ================= classifier tail =================
  {
    float part[4] = {0.f, 0.f, 0.f, 0.f};
    #pragma unroll
    for (int r = 0; r < 4; ++r) {
      const size_t base = ((size_t)(r0 + quad * 4 + r) * 64 + e) * 4;
      #pragma unroll
      for (int c = 0; c < 4; ++c)
        part[c] += hreg[r] * cvload(p.clsw0, base + c, fl);
    }
    #pragma unroll
    for (int c = 0; c < 4; ++c) {
      float v = part[c];
      v += __shfl_xor(v, 1);  v += __shfl_xor(v, 2);
      v += __shfl_xor(v, 4);  v += __shfl_xor(v, 8);
      v += __shfl_xor(v, 16); v += __shfl_xor(v, 32);
      if (lane == 0) s_s[wv * 4 + c] = v;
    }
    __syncthreads();
    if (tid < 4) {
      float tot = s_s[0 + tid] + s_s[4 + tid] + s_s[8 + tid] + s_s[12 + tid];
      gst(&p.clspart[(b * 16 + wg) * 4 + tid], tot);
    }
    __syncthreads();
    ptag(tgC, wg, 1);
    if (wg == 0) {
      wtag(tgC, 1);
      if (tid < 4) {
        float v = 0.f;
        for (int k = 0; k < 16; ++k) v += gld(&p.clspart[(b * 16 + k) * 4 + tid]);
        v += cvload(p.clsb0, tid, fl);
        if (fl) ((float*)p.out)[b * 4 + tid] = v;
        else    ((u16*)p.out)[b * 4 + tid] = f2b(v);
      }
    }
  }
}

extern "C" void kernel_launch(void* const* d_in, const int* in_sizes, int n_in,
                              void* d_out, int out_size, void* d_ws, size_t ws_size,
                              hipStream_t stream) {
  float* w = (float*)d_ws;
  size_t o = 0;
  auto alloc = [&](size_t n) { float* r = w + o; o += (n + 63) & ~(size_t)63; return r; };
  u64* xTp  = (u64*)alloc((size_t)B_ * 64 * 128);  // tgX-gated
  float* clspart = alloc(B_ * 16 * 4);             // tgC-gated
  u64* de1g = (u64*)alloc((size_t)B_ * N_ * 32);   // 16 u64/row, tag-gated
  u64* de2g = (u64*)alloc((size_t)B_ * N_ * 32);
  float* Eh = alloc((size_t)B_ * S_ * N_ * N_);    // t>=S guard: no memset
  const size_t zero_off = o;
  u64*   hgpT  = (u64*)alloc((size_t)B_ * 64 * 128);  // h(=0) at t=0
  u64*   degs  = (u64*)alloc((size_t)B_ * N_ * 2);    // epoch units
  u32*   tags  = (u32*)alloc(B_ * 256);               // wave-tags + tgX/tgC
  if (ws_size < o * sizeof(float)) return;

  (void)hipMemsetAsync(w + zero_off, 0, (o - zero_off) * sizeof(float), stream);

  Params p;
  p.x0  = d_in[0];  p.ew0 = d_in[1];
  p.gw0 = d_in[2];  p.gb0 = d_in[3];
  p.w10 = d_in[4];  p.b10 = d_in[5];
  p.w20 = d_in[6];  p.b20 = d_in[7];
  p.wzc0 = d_in[8];  p.bzc0 = d_in[9];  p.wzl0 = d_in[10]; p.bzl0 = d_in[11];
  p.wrc0 = d_in[12]; p.brc0 = d_in[13]; p.wrl0 = d_in[14]; p.brl0 = d_in[15];
  p.whc0 = d_in[16]; p.bhc0 = d_in[17]; p.whl0 = d_in[18]; p.bhl0 = d_in[19];
  p.clsw0 = d_in[20]; p.clsb0 = d_in[21];
  p.eidx = (const int*)d_in[22];
  p.Eh = Eh; p.clspart = clspart;
  p.degsum = degs;
  p.de1g = de1g; p.de2g = de2g; p.xTp = xTp; p.hgpT = hgpT;
  p.tags = tags; p.out = d_out;

  void* args[] = { &p };
  hipError_t ce = hipLaunchCooperativeKernel((const void*)dtgcn_main,
                                             dim3(B_ * G_), dim3(256), args, 0, stream);
  if (ce != hipSuccess) {
    (void)hipGetLastError();
    dtgcn_main<<<dim3(B_ * G_), dim3(256), 0, stream>>>(p);
  }
}

// Round 8
// 820.829 us; speedup vs baseline: 1.6338x; 1.6338x over previous
//
#include <hip/hip_runtime.h>
#include <hip/hip_bf16.h>

// DTGCN: B=16,N=256,T=64,W=12,H=64,ED=64,S=5,C=4,E=2048, FG=76
// R21c = R21 with WATCHDOG POLLS (diagnostic resubmission after two
// container-level failures; three full audits found no protocol defect).
// Every spin loop is bounded (SPIN_MAX ~ 2^20 iters ≈ 100ms >> any healthy
// wait). If a protocol stall exists, the kernel now TERMINATES with stale
// data -> passed:false + counters, instead of wedging the GPU.
// Algorithm identical to R21:
//   df = A^T (It @ gw) = A^T @ G,  G(t+1) = win(t+1)@gw_w + h(t)@gw_h
//   computed in P4 and published in h's former layout (feat-major u64 pack).
//   Phase A: wait G -> 16 MFMAs -> df. Removes m1 round-trip, df stage,
//   wave0 window straggler, x^T buffer + its prologue exchange.
// Protocol: A(t) waits tgG >= t+1; P4(t) publishes t+2; prologue publishes
// G(0)=win(0)@gw_w with tag 1. P3 de flow / deg epoch-units / Eh store-load /
// classifier are R19 verbatim.

typedef unsigned short u16;
typedef unsigned int u32;
typedef unsigned long long u64;
typedef __attribute__((ext_vector_type(8))) short bf16x8;
typedef __attribute__((ext_vector_type(4))) float f32x4;

#define B_ 16
#define N_ 256
#define T_ 64
#define W_ 12
#define S_ 5
#define E_ 2048
#define G_ 16
#define SPIN_MAX (1u << 20)

__device__ __forceinline__ float b2f(u16 u) {
  union { u32 i; float f; } v; v.i = ((u32)u) << 16; return v.f;
}
__device__ __forceinline__ u16 f2b(float f) {
  union { float f; u32 i; } v; v.f = f;
  u32 x = v.i; x += 0x7fff + ((x >> 16) & 1); return (u16)(x >> 16);
}
__device__ __forceinline__ float ftanh(float x) {
  float e = __expf(-2.f * fabsf(x));
  float t = (1.f - e) / (1.f + e);
  return x < 0.f ? -t : t;
}
__device__ __forceinline__ float fsigm(float x) { return 1.f / (1.f + __expf(-x)); }
__device__ __forceinline__ float cvload(const void* p, size_t i, int f) {
  return f ? ((const float*)p)[i] : b2f(((const u16*)p)[i]);
}
__device__ __forceinline__ u16 cvloadb(const void* p, size_t i, int f) {
  return f ? f2b(((const float*)p)[i]) : ((const u16*)p)[i];
}
__device__ __forceinline__ float gld(const float* p) {
  return __hip_atomic_load(p, __ATOMIC_RELAXED, __HIP_MEMORY_SCOPE_SYSTEM);
}
__device__ __forceinline__ void gst(float* p, float v) {
  __hip_atomic_store(p, v, __ATOMIC_RELAXED, __HIP_MEMORY_SCOPE_SYSTEM);
}
__device__ __forceinline__ u64 gld64(const u64* p) {
  return __hip_atomic_load(p, __ATOMIC_RELAXED, __HIP_MEMORY_SCOPE_SYSTEM);
}
__device__ __forceinline__ void gst64(u64* p, u64 v) {
  __hip_atomic_store(p, v, __ATOMIC_RELAXED, __HIP_MEMORY_SCOPE_SYSTEM);
}
__device__ __forceinline__ u32 gldu(const u32* p) {
  return __hip_atomic_load(p, __ATOMIC_RELAXED, __HIP_MEMORY_SCOPE_SYSTEM);
}
__device__ __forceinline__ f32x4 mfma16(bf16x8 a, bf16x8 b, f32x4 c) {
  return __builtin_amdgcn_mfma_f32_16x16x32_bf16(a, b, c, 0, 0, 0);
}
__device__ __forceinline__ bf16x8 ldfrag(const u16* p) { return *(const bf16x8*)p; }

struct Params {
  const void *x0, *ew0, *gw0, *gb0, *w10, *b10, *w20, *b20;
  const void *wzc0, *bzc0, *wzl0, *bzl0, *wrc0, *brc0, *wrl0, *brl0;
  const void *whc0, *bhc0, *whl0, *bhl0, *clsw0, *clsb0;
  const int* eidx;
  float *Eh, *clspart;
  u64 *degsum, *de1g, *de2g, *Ggp;
  u32 *tags;
  void* out;
};

// Bounded polls: on exhaustion, proceed (wrong data -> absmax fail, no wedge).
__device__ __forceinline__ void wtag(const u32* tg, u32 target) {
  const int k = threadIdx.x & 15;
  for (u32 s = 0; s < SPIN_MAX; ++s) {
    if (__all((int)(gldu(&tg[k]) >= target))) return;
    __builtin_amdgcn_s_sleep(1);
  }
}
__device__ __forceinline__ void wtag8(const u32* tg, int base, u32 target) {
  const int k = base + (threadIdx.x & 7);
  for (u32 s = 0; s < SPIN_MAX; ++s) {
    if (__all((int)(gldu(&tg[k]) >= target))) return;
    __builtin_amdgcn_s_sleep(1);
  }
}
__device__ __forceinline__ void ptag(u32* tg, int wg, u32 val) {
  if (threadIdx.x == 0)
    __hip_atomic_store(&tg[wg], val, __ATOMIC_RELAXED, __HIP_MEMORY_SCOPE_SYSTEM);
}

// ================= main persistent kernel (prologue + loop + cls tail) ======
__global__ void __launch_bounds__(256, 1) dtgcn_main(Params p) {
  __shared__ __align__(16) u16 s_union[18432];   // prologue scratch / G^T[64][264] / j1,j2
  __shared__ __align__(16) u16 s_gwHT[64 * 72];  // gw_h^T [e][64 pad 72]
  __shared__ __align__(16) u16 s_gwWT[64 * 32];  // gw_w^T [e][12 pad 32 zeros]
  __shared__ __align__(16) u16 s_xw[16 * 96];    // own-node x strip, left-pad 11
  __shared__ __align__(16) u16 s_w1T[64 * 72], s_w2T[64 * 72];
  __shared__ __align__(16) u16 s_gzT[64 * 72], s_grT[64 * 72], s_ghT[64 * 72];
  __shared__ __align__(16) u16 s_antO1[16 * 264], s_antO2[16 * 264];
  __shared__ float s_msum[16 * 257];
  __shared__ __align__(16) u16 s_de1I[16 * 72], s_de2I[16 * 72];
  __shared__ __align__(16) u16 s_hbf[16 * 72];
  __shared__ __align__(16) u16 s_dfhr[16 * 72];
  __shared__ float s_colv[16], s_degacc[16];
  __shared__ float s_y[256], s_dinv[256], s_s[16];
  __shared__ float s_uv[384], s_gb[64], s_b1[64], s_b2[64];
  __shared__ int s_flag;

  const int b = blockIdx.x & 15;
  const int wg = blockIdx.x >> 4;
  const int tid = threadIdx.x;
  const int lane = tid & 63;
  const int wv = tid >> 6;
  const int l = lane & 15;
  const int quad = lane >> 4;
  const int r0 = wg * 16;

  u64* de1g = p.de1g + (size_t)b * N_ * 16;
  u64* de2g = p.de2g + (size_t)b * N_ * 16;
  u64* Ggp  = p.Ggp + (size_t)b * 64 * 64;         // [feat e][node-quad 64]
  u64* degb = p.degsum + (size_t)b * N_;           // epoch units
  u32* tgDe = p.tags + b * 64;
  u32* tgG  = p.tags + b * 64 + 16;
  u32* tgC  = p.tags + b * 64 + 32;

  // ================= prologue =================
  // 1) dtype detect
  if (tid == 0) {
    const u16* q = (const u16*)p.x0;
    int c = 0;
    for (int i = 0; i < 256; ++i) {
      int ex = (q[i] >> 7) & 0xff;
      c += (ex >= 110 && ex <= 135);
    }
    s_flag = (c < 200) ? 1 : 0;   // 1 = fp32 inputs
  }
  __syncthreads();
  const int fl = s_flag;

  // 2) WG-local A-normalization (split-bf16 A^T own columns)
  {
    float* s_acol = (float*)s_union;          // [256][16]
    float* s_dg   = (float*)s_union + 4096;   // [256]
    for (int i = tid; i < 4096; i += 256) s_acol[i] = 0.f;
    s_dg[tid] = 0.f;
    __syncthreads();
    for (int e2 = tid; e2 < E_; e2 += 256) {
      const int sN = p.eidx[e2], dN = p.eidx[E_ + e2];
      const float wv2 = cvload(p.ew0, e2, fl);
      atomicAdd(&s_dg[dN], wv2);
      const int dl = dN - r0;
      if (dl >= 0 && dl < 16) atomicAdd(&s_acol[sN * 16 + dl], wv2);
    }
    __syncthreads();
    s_dg[tid] = rsqrtf(1.f + s_dg[tid]);
    __syncthreads();
    for (int idx = tid; idx < 4096; idx += 256) {
      const int jl = idx >> 8, i = idx & 255;
      float a = s_acol[i * 16 + jl] + ((i == r0 + jl) ? 1.f : 0.f);
      float v = s_dg[i] * a * s_dg[r0 + jl];
      u16 hi = f2b(v);
      s_antO1[jl * 264 + i] = hi;
      s_antO2[jl * 264 + i] = f2b(v - b2f(hi));
    }
  }

  // 3) weights / uv / biases / x-strip / zeroing
  for (int idx = tid; idx < 64 * 72; idx += 256) {
    const int ee = idx / 72, k = idx - ee * 72;
    s_gwHT[idx] = (k < 64) ? cvloadb(p.gw0, (12 + k) * 64 + ee, fl) : (u16)0;
  }
  for (int idx = tid; idx < 64 * 32; idx += 256) {
    const int ee = idx >> 5, w2 = idx & 31;
    s_gwWT[idx] = (w2 < 12) ? cvloadb(p.gw0, w2 * 64 + ee, fl) : (u16)0;
  }
  for (int idx = tid; idx < 16 * 96; idx += 256) {
    const int i = idx / 96, u = idx - i * 96;
    const int tt = u - (W_ - 1);
    s_xw[idx] = (tt >= 0 && tt < T_)
                ? f2b(cvload(p.x0, ((size_t)b * N_ + r0 + i) * T_ + tt, fl))
                : (u16)0;
  }
  for (int idx = tid; idx < 4096; idx += 256) {
    const int ee = idx >> 6, ff = idx & 63;
    s_w1T[ee * 72 + ff] = cvloadb(p.w10, ff * 64 + ee, fl);
    s_w2T[ee * 72 + ff] = cvloadb(p.w20, ff * 64 + ee, fl);
    s_gzT[ee * 72 + ff] = cvloadb(p.wzl0, 4096 + ff * 64 + ee, fl);
    s_grT[ee * 72 + ff] = cvloadb(p.wrl0, 4096 + ff * 64 + ee, fl);
    s_ghT[ee * 72 + ff] = cvloadb(p.whl0, 4096 + ff * 64 + ee, fl);
  }
  if (tid < 64) {
    const int e2 = tid;
    float uz = 0, vz = 0, ur = 0, vr = 0, uh = 0, vh = 0;
    for (int f = 0; f < 64; ++f) {
      float wz = cvload(p.wzl0, f * 64 + e2, fl);
      float wr = cvload(p.wrl0, f * 64 + e2, fl);
      float wh = cvload(p.whl0, f * 64 + e2, fl);
      uz += cvload(p.wzc0, f, fl) * wz; vz += cvload(p.bzc0, f, fl) * wz;
      ur += cvload(p.wrc0, f, fl) * wr; vr += cvload(p.brc0, f, fl) * wr;
      uh += cvload(p.whc0, f, fl) * wh; vh += cvload(p.bhc0, f, fl) * wh;
    }
    s_uv[0 * 64 + e2] = uz; s_uv[1 * 64 + e2] = vz + cvload(p.bzl0, e2, fl);
    s_uv[2 * 64 + e2] = ur; s_uv[3 * 64 + e2] = vr + cvload(p.brl0, e2, fl);
    s_uv[4 * 64 + e2] = uh; s_uv[5 * 64 + e2] = vh + cvload(p.bhl0, e2, fl);
    s_gb[tid] = cvload(p.gb0, tid, fl);
    s_b1[tid] = cvload(p.b10, tid, fl);
    s_b2[tid] = cvload(p.b20, tid, fl);
  }
  for (int idx = tid; idx < 16 * 257; idx += 256) s_msum[idx] = 0.f;
  for (int idx = tid; idx < 16 * 72; idx += 256) s_hbf[idx] = 0;
  if (tid < 16) s_degacc[tid] = 0.f;
  __syncthreads();

  const int e = wv * 16 + l;

  // 4) G(0) = win(0)@gw_w (h(-1)=0). B-side zero pad (w>=12) nullifies
  //    A-side garbage, so the raw strip window is safe at any t.
  {
    union { u16 a[8]; bf16x8 v; } ux;
    #pragma unroll
    for (int j = 0; j < 8; ++j) ux.a[j] = s_xw[l * 96 + quad * 8 + j];
    f32x4 g = mfma16(ux.v, ldfrag(&s_gwWT[e * 32 + quad * 8]),
                     (f32x4){0.f, 0.f, 0.f, 0.f});
    u64 gv = (u64)f2b(g[0]) | ((u64)f2b(g[1]) << 16)
           | ((u64)f2b(g[2]) << 32) | ((u64)f2b(g[3]) << 48);
    gst64(&Ggp[(size_t)e * 64 + (r0 >> 2) + quad], gv);
    __syncthreads();                         // drain publish
    ptag(tgG, wg, 1);
  }

  u16* s_gT = s_union;                  // [64][264] (feat-major G^T)
  u16* s_j1 = s_union;                  // [128][72]
  u16* s_j2 = s_union + 9216;

  float hreg[4] = {0.f, 0.f, 0.f, 0.f};

  for (int t = 0; t < T_; ++t) {
    float xv;
    // ---------- phase A: stage G^T, df (direct), de ----------
    {
      // prefetch x[t] for P4 (no dependencies)
      xv = cvload(p.x0, ((size_t)b * N_ + tid) * T_ + t, fl);
      const u32 gtgt = (u32)(t + 1);
      // half 0: G feats x nodes 0..127 (producer WGs 0..7)
      wtag8(tgG, 0, gtgt);
      {
        u64 th[8];
        #pragma unroll
        for (int q = 0; q < 8; ++q) {
          const int idx = q * 256 + tid;
          const int row = idx >> 5, c = idx & 31;
          th[q] = gld64(&Ggp[(size_t)row * 64 + c]);
        }
        #pragma unroll
        for (int q = 0; q < 8; ++q) {
          const int idx = q * 256 + tid;
          const int row = idx >> 5, c = idx & 31;
          *(u64*)&s_gT[row * 264 + c * 4] = th[q];
        }
      }
      __syncthreads();                       // bar A1: half-0 staged
      // half-1 poll + loads issued BEFORE half-0 MFMA (latency hidden)
      wtag8(tgG, 8, gtgt);
      u64 th1[8];
      #pragma unroll
      for (int q = 0; q < 8; ++q) {
        const int idx = q * 256 + tid;
        const int row = idx >> 5, c = idx & 31;
        th1[q] = gld64(&Ggp[(size_t)row * 64 + 32 + c]);
      }
      f32x4 dfa = {0.f, 0.f, 0.f, 0.f};
      #pragma unroll
      for (int ch = 0; ch < 4; ++ch) {
        const int io = ch * 32 + quad * 8;
        bf16x8 bfr = ldfrag(&s_gT[e * 264 + io]);
        dfa = mfma16(ldfrag(&s_antO1[l * 264 + io]), bfr, dfa);
        dfa = mfma16(ldfrag(&s_antO2[l * 264 + io]), bfr, dfa);
      }
      // stage half 1 (cols 128..255 — disjoint from half-0 MFMA reads)
      #pragma unroll
      for (int q = 0; q < 8; ++q) {
        const int idx = q * 256 + tid;
        const int row = idx >> 5, c = idx & 31;
        *(u64*)&s_gT[row * 264 + (32 + c) * 4] = th1[q];
      }
      __syncthreads();                       // bar A2: half-1 staged
      #pragma unroll
      for (int ch = 4; ch < 8; ++ch) {
        const int io = ch * 32 + quad * 8;
        bf16x8 bfr = ldfrag(&s_gT[e * 264 + io]);
        dfa = mfma16(ldfrag(&s_antO1[l * 264 + io]), bfr, dfa);
        dfa = mfma16(ldfrag(&s_antO2[l * 264 + io]), bfr, dfa);
      }
      #pragma unroll
      for (int r = 0; r < 4; ++r)
        s_dfhr[(quad * 4 + r) * 72 + e] = f2b(dfa[r] + s_gb[e]);
      __syncthreads();                       // bar A3: df ready
      // de1/de2: compute, write local strips, publish from regs (shfl-packed)
      {
        f32x4 E1, E2;
        #pragma unroll
        for (int r = 0; r < 4; ++r) { E1[r] = s_b1[e]; E2[r] = s_b2[e]; }
        #pragma unroll
        for (int ks = 0; ks < 2; ++ks) {
          bf16x8 afr = ldfrag(&s_dfhr[l * 72 + ks * 32 + quad * 8]);
          E1 = mfma16(afr, ldfrag(&s_w1T[e * 72 + ks * 32 + quad * 8]), E1);
          E2 = mfma16(afr, ldfrag(&s_w2T[e * 72 + ks * 32 + quad * 8]), E2);
        }
        u32 v1[4], v2[4];
        #pragma unroll
        for (int r = 0; r < 4; ++r) {
          v1[r] = (u32)f2b(ftanh(E1[r]));
          v2[r] = (u32)f2b(ftanh(E2[r]));
          s_de1I[(quad * 4 + r) * 72 + e] = (u16)v1[r];
          s_de2I[(quad * 4 + r) * 72 + e] = (u16)v2[r];
        }
        // pack 4 consecutive feature cols into one u64 per row (lanes l%4==0)
        #pragma unroll
        for (int r = 0; r < 4; ++r) {
          u32 a1 = (u32)__shfl_xor((int)v1[r], 1);
          u32 a2 = (u32)__shfl_xor((int)v2[r], 1);
          u32 ev1 = (l & 1) ? a1 : v1[r], od1 = (l & 1) ? v1[r] : a1;
          u32 ev2 = (l & 1) ? a2 : v2[r], od2 = (l & 1) ? v2[r] : a2;
          u32 w1 = ev1 | (od1 << 16), w2 = ev2 | (od2 << 16);
          u32 x1 = (u32)__shfl_xor((int)w1, 2);
          u32 x2 = (u32)__shfl_xor((int)w2, 2);
          u64 q1 = (l & 2) ? ((u64)x1 | ((u64)w1 << 32)) : ((u64)w1 | ((u64)x1 << 32));
          u64 q2 = (l & 2) ? ((u64)x2 | ((u64)w2 << 32)) : ((u64)w2 | ((u64)x2 << 32));
          if ((l & 3) == 0) {
            const size_t ro = (size_t)(r0 + quad * 4 + r) * 16 + wv * 4 + (l >> 2);
            gst64(&de1g[ro], q1);
            gst64(&de2g[ro], q2);
          }
        }
      }
      __syncthreads();   // bar A4: drains de1I LDS writes + publish stores
      ptag(tgDe, wg, (u32)(t + 1));
    }

    // ---------- P3: Et column strip; Eh/Msum/deg (R19 verbatim) ----------
    {
      const int sidx = t % S_;
      float* Ehc = p.Eh + ((size_t)((b * S_ + sidx) * G_ + wg)) * (N_ * 16);
      if (tid < 16) s_colv[tid] = 0.f;
      bf16x8 bq1[2], bq2[2];
      #pragma unroll
      for (int ks = 0; ks < 2; ++ks) {
        bq1[ks] = ldfrag(&s_de1I[l * 72 + ks * 32 + quad * 8]);
        bq2[ks] = ldfrag(&s_de2I[l * 72 + ks * 32 + quad * 8]);
      }
      const int havold = (t >= S_);
      float old0[2][4] = {{0.f, 0.f, 0.f, 0.f}, {0.f, 0.f, 0.f, 0.f}};
      float old1[2][4] = {{0.f, 0.f, 0.f, 0.f}, {0.f, 0.f, 0.f, 0.f}};
      if (havold) {
        #pragma unroll
        for (int mt2 = 0; mt2 < 2; ++mt2) {
          const int mt = wv * 2 + mt2;
          #pragma unroll
          for (int r = 0; r < 4; ++r) {
            const int i0 = mt * 16 + quad * 4 + r;
            old0[mt2][r] = Ehc[(size_t)i0 * 16 + l];
            old1[mt2][r] = Ehc[(size_t)(128 + i0) * 16 + l];
          }
        }
      }
      const u32 dtgt = (u32)(t + 1);
      wtag8(tgDe, 0, dtgt);
      u64 t1a[8], t2a[8];
      #pragma unroll
      for (int q = 0; q < 8; ++q) {
        const int idx = q * 256 + tid;
        const int row = idx >> 4, c = idx & 15;
        t1a[q] = gld64(&de1g[(size_t)row * 16 + c]);
        t2a[q] = gld64(&de2g[(size_t)row * 16 + c]);
      }
      #pragma unroll
      for (int q = 0; q < 8; ++q) {
        const int idx = q * 256 + tid;
        const int row = idx >> 4, c = idx & 15;
        *(u64*)&s_j1[row * 72 + c * 4] = t1a[q];
        *(u64*)&s_j2[row * 72 + c * 4] = t2a[q];
      }
      __syncthreads();                       // bar P3-1: half-0 staged
      wtag8(tgDe, 8, dtgt);
      u64 t1b[8], t2b[8];
      #pragma unroll
      for (int q = 0; q < 8; ++q) {
        const int idx = q * 256 + tid;
        const int row = idx >> 4, c = idx & 15;
        t1b[q] = gld64(&de1g[(size_t)(128 + row) * 16 + c]);
        t2b[q] = gld64(&de2g[(size_t)(128 + row) * 16 + c]);
      }
      float dcacc = 0.f;
      #pragma unroll
      for (int mt2 = 0; mt2 < 2; ++mt2) {
        const int mt = wv * 2 + mt2;
        f32x4 D1 = {0.f, 0.f, 0.f, 0.f}, D2 = {0.f, 0.f, 0.f, 0.f};
        #pragma unroll
        for (int ks = 0; ks < 2; ++ks) {
          bf16x8 a1 = ldfrag(&s_j1[(mt * 16 + l) * 72 + ks * 32 + quad * 8]);
          bf16x8 a2 = ldfrag(&s_j2[(mt * 16 + l) * 72 + ks * 32 + quad * 8]);
          D1 = mfma16(a1, bq2[ks], D1);
          D2 = mfma16(a2, bq1[ks], D2);
        }
        #pragma unroll
        for (int r = 0; r < 4; ++r) {
          const int i = mt * 16 + quad * 4 + r;
          float d = ftanh(D1[r] - D2[r]);
          float eN = fmaxf(d, 0.f);
          float dd = eN - old0[mt2][r];
          Ehc[(size_t)i * 16 + l] = eN;
          s_msum[l * 257 + i] += dd;
          dcacc += dd;
        }
      }
      __syncthreads();                       // bar P3-2: half-0 j reads done
      #pragma unroll
      for (int q = 0; q < 8; ++q) {
        const int idx = q * 256 + tid;
        const int row = idx >> 4, c = idx & 15;
        *(u64*)&s_j1[row * 72 + c * 4] = t1b[q];
        *(u64*)&s_j2[row * 72 + c * 4] = t2b[q];
      }
      __syncthreads();                       // bar P3-3: half-1 staged
      #pragma unroll
      for (int mt2 = 0; mt2 < 2; ++mt2) {
        const int mt = wv * 2 + mt2;
        f32x4 D1 = {0.f, 0.f, 0.f, 0.f}, D2 = {0.f, 0.f, 0.f, 0.f};
        #pragma unroll
        for (int ks = 0; ks < 2; ++ks) {
          bf16x8 a1 = ldfrag(&s_j1[(mt * 16 + l) * 72 + ks * 32 + quad * 8]);
          bf16x8 a2 = ldfrag(&s_j2[(mt * 16 + l) * 72 + ks * 32 + quad * 8]);
          D1 = mfma16(a1, bq2[ks], D1);
          D2 = mfma16(a2, bq1[ks], D2);
        }
        #pragma unroll
        for (int r = 0; r < 4; ++r) {
          const int i = 128 + mt * 16 + quad * 4 + r;
          float d = ftanh(D1[r] - D2[r]);
          float eN = fmaxf(d, 0.f);
          float dd = eN - old1[mt2][r];
          Ehc[(size_t)i * 16 + l] = eN;
          s_msum[l * 257 + i] += dd;
          dcacc += dd;
        }
      }
      dcacc += __shfl_xor(dcacc, 16);
      dcacc += __shfl_xor(dcacc, 32);
      if (lane < 16) atomicAdd(&s_colv[lane], dcacc);
      __syncthreads();                       // bar P3-4
      if (tid < 16) {
        float nd = s_degacc[tid] + s_colv[tid];
        s_degacc[tid] = nd;
        union { float f; u32 i; } cv; cv.f = nd;
        gst64(&degb[r0 + tid], (u64)cv.i | ((u64)dtgt << 32));
      }
      // no drain barrier / tag: deg units are self-validating
    }

    // ---------- P4: gates, dinv/y, s, GRU, G publish ----------
    {
      f32x4 azh = {0.f, 0.f, 0.f, 0.f}, arh = {0.f, 0.f, 0.f, 0.f};
      #pragma unroll
      for (int ks = 0; ks < 2; ++ks) {
        bf16x8 afr = ldfrag(&s_hbf[l * 72 + ks * 32 + quad * 8]);
        azh = mfma16(afr, ldfrag(&s_gzT[e * 72 + ks * 32 + quad * 8]), azh);
        arh = mfma16(afr, ldfrag(&s_grT[e * 72 + ks * 32 + quad * 8]), arh);
      }
      const u32 dgt = (u32)(t + 1);
      u64 du = 0;
      for (u32 sp = 0; sp < SPIN_MAX; ++sp) {
        du = gld64(&degb[tid]);
        if (__all((int)((u32)(du >> 32) >= dgt))) break;
        __builtin_amdgcn_s_sleep(1);
      }
      const float cnt = (float)((t + 1 < S_) ? (t + 1) : S_);
      const float invc = 1.f / cnt;
      {
        union { u32 i; float f; } dv; dv.i = (u32)du;
        float dg = 1.f + dv.f * invc;
        float di = rsqrtf(dg);
        s_dinv[tid] = di;
        s_y[tid] = di * xv;                  // xv prefetched in phase A
      }
      __syncthreads();                       // bar P4-1
      // s: remapped owners + k-rotated reads + butterfly reduce
      {
        const int jl = tid >> 4, cc = tid & 15;
        float part = 0.f;
        #pragma unroll
        for (int k = 0; k < 16; ++k) {
          const int i = cc * 16 + ((k + cc) & 15);
          part += s_msum[jl * 257 + i] * s_y[i];
        }
        part += __shfl_xor(part, 1);
        part += __shfl_xor(part, 2);
        part += __shfl_xor(part, 4);
        part += __shfl_xor(part, 8);
        if (cc == 0) {
          const int j = r0 + jl;
          s_s[jl] = s_dinv[j] * (part * invc + s_y[j]);
        }
      }
      __syncthreads();                       // bar P4-2
      float sv[4];
      #pragma unroll
      for (int r = 0; r < 4; ++r) sv[r] = s_s[quad * 4 + r];
      float zz[4], rr2[4];
      #pragma unroll
      for (int r = 0; r < 4; ++r) {
        zz[r]  = fsigm(azh[r] + s_uv[0 * 64 + e] * sv[r] + s_uv[1 * 64 + e]);
        rr2[r] = fsigm(arh[r] + s_uv[2 * 64 + e] * sv[r] + s_uv[3 * 64 + e]);
      }
      #pragma unroll
      for (int r = 0; r < 4; ++r)
        s_dfhr[(quad * 4 + r) * 72 + e] = f2b(hreg[r] * rr2[r]);
      __syncthreads();                       // bar P4-3
      f32x4 ah;
      #pragma unroll
      for (int r = 0; r < 4; ++r) ah[r] = s_uv[4 * 64 + e] * sv[r] + s_uv[5 * 64 + e];
      #pragma unroll
      for (int ks = 0; ks < 2; ++ks) {
        bf16x8 afr = ldfrag(&s_dfhr[l * 72 + ks * 32 + quad * 8]);
        ah = mfma16(afr, ldfrag(&s_ghT[e * 72 + ks * 32 + quad * 8]), ah);
      }
      #pragma unroll
      for (int r = 0; r < 4; ++r) {
        float ht = ftanh(ah[r]);
        hreg[r] = zz[r] * hreg[r] + (1.f - zz[r]) * ht;
      }
      // store new h locally (no global h publish in this scheme)
      s_hbf[(quad * 4 + 0) * 72 + e] = f2b(hreg[0]);
      s_hbf[(quad * 4 + 1) * 72 + e] = f2b(hreg[1]);
      s_hbf[(quad * 4 + 2) * 72 + e] = f2b(hreg[2]);
      s_hbf[(quad * 4 + 3) * 72 + e] = f2b(hreg[3]);
      __syncthreads();                       // bar P4-4: h(t) visible in LDS
      // G(t+1) = win(t+1)@gw_w + h(t)@gw_h ; publish in h's former layout
      {
        union { u16 a[8]; bf16x8 v; } ux;
        const int ub = (t + 1) + quad * 8;
        #pragma unroll
        for (int j = 0; j < 8; ++j) ux.a[j] = s_xw[l * 96 + ub + j];
        f32x4 g = mfma16(ux.v, ldfrag(&s_gwWT[e * 32 + quad * 8]),
                         (f32x4){0.f, 0.f, 0.f, 0.f});
        #pragma unroll
        for (int ks = 0; ks < 2; ++ks)
          g = mfma16(ldfrag(&s_hbf[l * 72 + ks * 32 + quad * 8]),
                     ldfrag(&s_gwHT[e * 72 + ks * 32 + quad * 8]), g);
        u64 gv = (u64)f2b(g[0]) | ((u64)f2b(g[1]) << 16)
               | ((u64)f2b(g[2]) << 32) | ((u64)f2b(g[3]) << 48);
        gst64(&Ggp[(size_t)e * 64 + (r0 >> 2) + quad], gv);
      }
      __syncthreads();                       // bar P4-5: drain G publish
      ptag(tgG, wg, (u32)(t + 2));
    }
  }

  // ================= classifier tail =================
  {
    float part[4] = {0.f, 0.f, 0.f, 0.f};
    #pragma unroll
    for (int r = 0; r < 4; ++r) {
      const size_t base = ((size_t)(r0 + quad * 4 + r) * 64 + e) * 4;
      #pragma unroll
      for (int c = 0; c < 4; ++c)
        part[c] += hreg[r] * cvload(p.clsw0, base + c, fl);
    }
    #pragma unroll
    for (int c = 0; c < 4; ++c) {
      float v = part[c];
      v += __shfl_xor(v, 1);  v += __shfl_xor(v, 2);
      v += __shfl_xor(v, 4);  v += __shfl_xor(v, 8);
      v += __shfl_xor(v, 16); v += __shfl_xor(v, 32);
      if (lane == 0) s_s[wv * 4 + c] = v;
    }
    __syncthreads();
    if (tid < 4) {
      float tot = s_s[0 + tid] + s_s[4 + tid] + s_s[8 + tid] + s_s[12 + tid];
      gst(&p.clspart[(b * 16 + wg) * 4 + tid], tot);
    }
    __syncthreads();
    ptag(tgC, wg, 1);
    if (wg == 0) {
      wtag(tgC, 1);
      if (tid < 4) {
        float v = 0.f;
        for (int k = 0; k < 16; ++k) v += gld(&p.clspart[(b * 16 + k) * 4 + tid]);
        v += cvload(p.clsb0, tid, fl);
        if (fl) ((float*)p.out)[b * 4 + tid] = v;
        else    ((u16*)p.out)[b * 4 + tid] = f2b(v);
      }
    }
  }
}

extern "C" void kernel_launch(void* const* d_in, const int* in_sizes, int n_in,
                              void* d_out, int out_size, void* d_ws, size_t ws_size,
                              hipStream_t stream) {
  float* w = (float*)d_ws;
  size_t o = 0;
  auto alloc = [&](size_t n) { float* r = w + o; o += (n + 63) & ~(size_t)63; return r; };
  float* clspart = alloc(B_ * 16 * 4);             // tgC-gated
  u64* de1g = (u64*)alloc((size_t)B_ * N_ * 32);   // 16 u64/row, tgDe-gated
  u64* de2g = (u64*)alloc((size_t)B_ * N_ * 32);
  u64* Ggp  = (u64*)alloc((size_t)B_ * 64 * 128);  // tgG-gated (prologue pub)
  float* Eh = alloc((size_t)B_ * S_ * N_ * N_);    // t>=S guard: no memset
  const size_t zero_off = o;
  u64*   degs  = (u64*)alloc((size_t)B_ * N_ * 2); // epoch units: MUST zero
  u32*   tags  = (u32*)alloc(B_ * 64);             // MUST zero
  if (ws_size < o * sizeof(float)) return;

  (void)hipMemsetAsync(w + zero_off, 0, (o - zero_off) * sizeof(float), stream);

  Params p;
  p.x0  = d_in[0];  p.ew0 = d_in[1];
  p.gw0 = d_in[2];  p.gb0 = d_in[3];
  p.w10 = d_in[4];  p.b10 = d_in[5];
  p.w20 = d_in[6];  p.b20 = d_in[7];
  p.wzc0 = d_in[8];  p.bzc0 = d_in[9];  p.wzl0 = d_in[10]; p.bzl0 = d_in[11];
  p.wrc0 = d_in[12]; p.brc0 = d_in[13]; p.wrl0 = d_in[14]; p.brl0 = d_in[15];
  p.whc0 = d_in[16]; p.bhc0 = d_in[17]; p.whl0 = d_in[18]; p.bhl0 = d_in[19];
  p.clsw0 = d_in[20]; p.clsb0 = d_in[21];
  p.eidx = (const int*)d_in[22];
  p.Eh = Eh; p.clspart = clspart;
  p.degsum = degs;
  p.de1g = de1g; p.de2g = de2g; p.Ggp = Ggp;
  p.tags = tags; p.out = d_out;

  void* args[] = { &p };
  hipError_t ce = hipLaunchCooperativeKernel((const void*)dtgcn_main,
                                             dim3(B_ * G_), dim3(256), args, 0, stream);
  if (ce != hipSuccess) {
    (void)hipGetLastError();
    dtgcn_main<<<dim3(B_ * G_), dim3(256), 0, stream>>>(p);
  }
}